// Round 5
// baseline (3542.747 us; speedup 1.0000x reference)
//
#include <hip/hip_runtime.h>

#define DD 48
#define HF 256
#define WF 320
#define HH 128
#define WH 160
#define NPF (HF * WF)     // 81920
#define NPH (HH * WH)     // 20480
#define S1SZ (8 * NPF)    // one s1-class slice (floats)
#define S2SZ (16 * NPH)   // one s2-class slice (floats)

__device__ __forceinline__ float sigf(float x) { return 1.0f / (1.0f + __expf(-x)); }
__device__ __forceinline__ float tanh_(float x) {
    float e = __expf(2.0f * x);
    return 1.0f - 2.0f / (e + 1.0f);
}

// ---- 1-px taps: 3x3 window, clamped + masked ------------------------------
template<int Ht, int Wt>
__device__ __forceinline__ void taps1v(int y, int x, int* off, float* msk) {
    const int xm = max(x - 1, 0), xp = min(x + 1, Wt - 1);
    const float cm0 = (x > 0) ? 1.0f : 0.0f;
    const float cm2 = (x < Wt - 1) ? 1.0f : 0.0f;
#pragma unroll
    for (int r = 0; r < 3; ++r) {
        const int yy = y - 1 + r;
        const float rm = ((unsigned)yy < (unsigned)Ht) ? 1.0f : 0.0f;
        const int rb = min(max(yy, 0), Ht - 1) * Wt;
        off[r * 3 + 0] = rb + xm; msk[r * 3 + 0] = rm * cm0;
        off[r * 3 + 1] = rb + x;  msk[r * 3 + 1] = rm;
        off[r * 3 + 2] = rb + xp; msk[r * 3 + 2] = rm * cm2;
    }
}

// acc 1 px x COUT over CI channels (9 loads/ci shared by all couts)
template<int CI, int COUT>
__device__ __forceinline__ void acc1(
    const float* __restrict__ in, int cs,
    const float* __restrict__ w, int wcs,
    const int* off, const float* msk, float* a)
{
#pragma unroll 2
    for (int ci = 0; ci < CI; ++ci) {
        const float* p = in + ci * cs;
        float v[9];
#pragma unroll
        for (int k = 0; k < 9; ++k) v[k] = p[off[k]] * msk[k];
        const float* wp = w + ci * 9;
#pragma unroll
        for (int j = 0; j < COUT; ++j) {
            const float* wc = wp + j * wcs;
#pragma unroll
            for (int k = 0; k < 9; ++k) a[j] = fmaf(v[k], wc[k], a[j]);
        }
    }
}

// ---- vertical 2-px conv core (kept for cand1 / conv2) ---------------------
template<int Ht, int Wt>
__device__ __forceinline__ void taps2v(int y0, int x, int* off, float* msk) {
    const int xm = max(x - 1, 0), xp = min(x + 1, Wt - 1);
    const float cm0 = (x > 0) ? 1.0f : 0.0f;
    const float cm2 = (x < Wt - 1) ? 1.0f : 0.0f;
#pragma unroll
    for (int r = 0; r < 4; ++r) {
        const int yy = y0 - 1 + r;
        const float rm = ((unsigned)yy < (unsigned)Ht) ? 1.0f : 0.0f;
        const int rb = min(max(yy, 0), Ht - 1) * Wt;
        off[r * 3 + 0] = rb + xm; msk[r * 3 + 0] = rm * cm0;
        off[r * 3 + 1] = rb + x;  msk[r * 3 + 1] = rm;
        off[r * 3 + 2] = rb + xp; msk[r * 3 + 2] = rm * cm2;
    }
}

template<int CI, int COUT>
__device__ __forceinline__ void acc2v(
    const float* __restrict__ in, int cs,
    const float* __restrict__ w, int wcs,
    const int* off, const float* msk,
    float* a0, float* a1)
{
#pragma unroll 2
    for (int ci = 0; ci < CI; ++ci) {
        const float* p = in + ci * cs;
        float v[12];
#pragma unroll
        for (int k = 0; k < 12; ++k) v[k] = p[off[k]] * msk[k];
        const float* wp = w + ci * 9;
#pragma unroll
        for (int j = 0; j < COUT; ++j) {
            const float* wc = wp + j * wcs;
#pragma unroll
            for (int r = 0; r < 3; ++r) {
#pragma unroll
                for (int c = 0; c < 3; ++c) {
                    a0[j] = fmaf(v[r * 3 + c],       wc[r * 3 + c], a0[j]);
                    a1[j] = fmaf(v[(r + 1) * 3 + c], wc[r * 3 + c], a1[j]);
                }
            }
        }
    }
}

// ---- conv1 role (batched/prologue): vertical 4-px strip per thread --------
__device__ __forceinline__ void conv1_role(
    const float* __restrict__ x, const float* __restrict__ w,
    const float* __restrict__ b, float* __restrict__ o_slice,
    int dsl, int pb)
{
    const int t = pb * 256 + threadIdx.x;   // [0, 20480) per slice
    const int xc = t % WF;
    const int yb = (t / WF) * 4;
    const float* __restrict__ xin = x + (long)dsl * NPF;
    const int cxm = max(xc - 1, 0), cxp = min(xc + 1, WF - 1);
    const float cmm = (xc > 0) ? 1.0f : 0.0f;
    const float cmp = (xc < WF - 1) ? 1.0f : 0.0f;
    int off[18]; float msk[18];
#pragma unroll
    for (int r = 0; r < 6; ++r) {
        const int yy = yb - 1 + r;
        const float rm = ((unsigned)yy < (unsigned)HF) ? 1.0f : 0.0f;
        const int rb = min(max(yy, 0), HF - 1) * WF;
        off[r * 3 + 0] = rb + cxm; msk[r * 3 + 0] = rm * cmm;
        off[r * 3 + 1] = rb + xc;  msk[r * 3 + 1] = rm;
        off[r * 3 + 2] = rb + cxp; msk[r * 3 + 2] = rm * cmp;
    }
    float acc[4][8];
#pragma unroll
    for (int j = 0; j < 8; ++j) {
        const float bj = b[j];
#pragma unroll
        for (int q = 0; q < 4; ++q) acc[q][j] = bj;
    }
#pragma unroll 2
    for (int ci = 0; ci < 32; ++ci) {
        const float* p = xin + (long)ci * (DD * NPF);
        float v[18];
#pragma unroll
        for (int k = 0; k < 18; ++k) v[k] = p[off[k]] * msk[k];
        const float* wp = w + ci * 9;                 // w (8,32,3,3): cout stride 288
#pragma unroll
        for (int j = 0; j < 8; ++j) {
            const float* wc = wp + j * (32 * 9);
#pragma unroll
            for (int q = 0; q < 4; ++q) {
#pragma unroll
                for (int r = 0; r < 3; ++r) {
                    acc[q][j] = fmaf(v[(q + r) * 3 + 0], wc[r * 3 + 0], acc[q][j]);
                    acc[q][j] = fmaf(v[(q + r) * 3 + 1], wc[r * 3 + 1], acc[q][j]);
                    acc[q][j] = fmaf(v[(q + r) * 3 + 2], wc[r * 3 + 2], acc[q][j]);
                }
            }
        }
    }
    float* o = o_slice + yb * WF + xc;
#pragma unroll
    for (int j = 0; j < 8; ++j)
#pragma unroll
        for (int q = 0; q < 4; ++q)
            o[j * NPF + q * WF] = fmaxf(acc[q][j], 0.0f);
}

// ---- conv1 role (chain-folded): 1 px per thread, 320 blocks/slice ---------
__device__ __forceinline__ void conv1p_role(
    const float* __restrict__ x, const float* __restrict__ w,
    const float* __restrict__ b, float* __restrict__ o_slice,
    int dsl, int pb)
{
    const int t = pb * 256 + threadIdx.x;   // [0, NPF)
    const int y = t / WF, xc = t - y * WF;
    const float* __restrict__ xin = x + (long)dsl * NPF;
    int off[9]; float msk[9];
    taps1v<HF, WF>(y, xc, off, msk);
    float acc[8];
#pragma unroll
    for (int j = 0; j < 8; ++j) acc[j] = b[j];
    acc1<32, 8>(xin, DD * NPF, w, 32 * 9, off, msk, acc);
    float* o = o_slice + t;
#pragma unroll
    for (int j = 0; j < 8; ++j) o[j * NPF] = fmaxf(acc[j], 0.0f);
}

__global__ __launch_bounds__(256) void k_conv1(
    const float* __restrict__ x, const float* __restrict__ w,
    const float* __restrict__ b, float* __restrict__ out,
    int d0, int ostride)
{
    conv1_role(x, w, b, out + (long)blockIdx.z * ostride, d0 + blockIdx.z, blockIdx.x);
}

// ---- gates1: 1px, all 16 couts in one pass (no redundant input reads) -----
__device__ __forceinline__ void gates1_role(
    const float* __restrict__ c1, const float* __restrict__ s1,
    const float* __restrict__ w, const float* __restrict__ b,
    float* __restrict__ rh, float* __restrict__ u, int pb)
{
    const int t = pb * 256 + threadIdx.x;    // [0, NPF)
    const int y = t / WF, x = t - y * WF;
    int off[9]; float msk[9];
    taps1v<HF, WF>(y, x, off, msk);
    float a[16];
#pragma unroll
    for (int j = 0; j < 16; ++j) a[j] = b[j];
    // wg1 (16,16,3,3): cout stride 144; ci 0..7 = c1, 8..15 = s1 (offset 72)
    acc1<8, 16>(c1, NPF, w, 144, off, msk, a);
    acc1<8, 16>(s1, NPF, w + 72, 144, off, msk, a);
#pragma unroll
    for (int j = 0; j < 8; ++j) {
        const int o = j * NPF + t;
        rh[o] = sigf(a[j]) * s1[o];
    }
#pragma unroll
    for (int j = 0; j < 8; ++j)
        u[j * NPF + t] = sigf(a[8 + j]);
}

// ---- gates2: 1px, CO=8, 4 cout-groups -------------------------------------
__device__ __forceinline__ void gates2_role(
    const float* __restrict__ c2, const float* __restrict__ s2,
    const float* __restrict__ w, const float* __restrict__ b,
    float* __restrict__ rh, float* __restrict__ u, int pb, int cog)
{
    const int t = pb * 256 + threadIdx.x;    // [0, NPH)
    const int y = t / WH, x = t - y * WH;
    const int co0 = cog * 8;
    int off[9]; float msk[9];
    taps1v<HH, WH>(y, x, off, msk);
    float a[8];
#pragma unroll
    for (int j = 0; j < 8; ++j) a[j] = b[co0 + j];
    // wg2 (32,32,3,3): cout stride 288; ci 0..15 = c2, 16..31 = s2 (offset 144)
    const float* wb = w + co0 * 288;
    acc1<16, 8>(c2, NPH, wb, 288, off, msk, a);
    acc1<16, 8>(s2, NPH, wb + 144, 288, off, msk, a);
    if (co0 < 16) {
#pragma unroll
        for (int j = 0; j < 8; ++j) {
            const int o = (co0 + j) * NPH + t;
            rh[o] = sigf(a[j]) * s2[o];
        }
    } else {
#pragma unroll
        for (int j = 0; j < 8; ++j)
            u[(co0 - 16 + j) * NPH + t] = sigf(a[j]);
    }
}

// ---- cand1: vertical 2px, all 8 couts -------------------------------------
__device__ __forceinline__ void cand1_role(
    const float* __restrict__ a_in, const float* __restrict__ rh,
    const float* __restrict__ w, const float* __restrict__ b,
    const float* __restrict__ u, const float* __restrict__ sprev,
    float* __restrict__ sout, int pb)
{
    const int t = pb * 256 + threadIdx.x;    // [0, NPF/2)
    const int x = t % WF, y0 = (t / WF) * 2;
    int off[12]; float msk[12];
    taps2v<HF, WF>(y0, x, off, msk);
    float a0[8], a1[8];
#pragma unroll
    for (int j = 0; j < 8; ++j) { a0[j] = b[j]; a1[j] = b[j]; }
    // wc1 (8,16,3,3): cout stride 144; ci 0..7 = c1, 8..15 = rh (offset 72)
    acc2v<8, 8>(a_in, NPF, w, 144, off, msk, a0, a1);
    acc2v<8, 8>(rh, NPF, w + 72, 144, off, msk, a0, a1);
    const int p0 = y0 * WF + x;
#pragma unroll
    for (int j = 0; j < 8; ++j) {
        const int o = j * NPF + p0;
        float c0 = tanh_(a0[j]);
        float c1 = tanh_(a1[j]);
        sout[o]      = fmaf(u[o],      sprev[o]      - c0, c0);
        sout[o + WF] = fmaf(u[o + WF], sprev[o + WF] - c1, c1);
    }
}

// ---- cand2: 1px, CO=8, 2 cout-groups --------------------------------------
__device__ __forceinline__ void cand2_role(
    const float* __restrict__ a_in, const float* __restrict__ rh,
    const float* __restrict__ w, const float* __restrict__ b,
    const float* __restrict__ u, const float* __restrict__ sprev,
    float* __restrict__ sout, int pb, int cog)
{
    const int t = pb * 256 + threadIdx.x;    // [0, NPH)
    const int y = t / WH, x = t - y * WH;
    const int co0 = cog * 8;
    int off[9]; float msk[9];
    taps1v<HH, WH>(y, x, off, msk);
    float a[8];
#pragma unroll
    for (int j = 0; j < 8; ++j) a[j] = b[co0 + j];
    // wc2 (16,32,3,3): cout stride 288; ci 0..15 = c2, 16..31 = rh (offset 144)
    const float* wb = w + co0 * 288;
    acc1<16, 8>(a_in, NPH, wb, 288, off, msk, a);
    acc1<16, 8>(rh, NPH, wb + 144, 288, off, msk, a);
#pragma unroll
    for (int j = 0; j < 8; ++j) {
        const int o = (co0 + j) * NPH + t;
        float c = tanh_(a[j]);
        sout[o] = fmaf(u[o], sprev[o] - c, c);
    }
}

// ---- conv2 role (vertical 2px out): stride-2 3x3 pad1 ---------------------
__device__ __forceinline__ void conv2_role(
    const float* __restrict__ s1, const float* __restrict__ w,
    const float* __restrict__ b, float* __restrict__ c2, int pb, int cog)
{
    const int t = pb * 256 + threadIdx.x;           // [0, NPH/2)
    const int x = t % WH, yp = t / WH;              // yp in [0, HH/2)
    const int y0 = 2 * yp;
    const int co0 = cog * 8;
    int off[15]; float msk[15];
    {
        const int cxm = max(2 * x - 1, 0);
        const float cmm = (x > 0) ? 1.0f : 0.0f;
#pragma unroll
        for (int r = 0; r < 5; ++r) {
            const int yy = 4 * yp - 1 + r;          // <= HF-1
            const float rm = (yy >= 0) ? 1.0f : 0.0f;
            const int rb = max(yy, 0) * WF;
            off[r * 3 + 0] = rb + cxm;       msk[r * 3 + 0] = rm * cmm;
            off[r * 3 + 1] = rb + 2 * x;     msk[r * 3 + 1] = rm;
            off[r * 3 + 2] = rb + 2 * x + 1; msk[r * 3 + 2] = rm;
        }
    }
    float a0[8], a1[8];
#pragma unroll
    for (int j = 0; j < 8; ++j) { a0[j] = b[co0 + j]; a1[j] = b[co0 + j]; }
#pragma unroll 2
    for (int ci = 0; ci < 8; ++ci) {
        const float* p = s1 + ci * NPF;
        float v[15];
#pragma unroll
        for (int k = 0; k < 15; ++k) v[k] = p[off[k]] * msk[k];
        const float* wp = w + co0 * 72 + ci * 9;   // w (16,8,3,3), cout stride 72
#pragma unroll
        for (int j = 0; j < 8; ++j) {
            const float* wc = wp + j * 72;
#pragma unroll
            for (int r = 0; r < 3; ++r) {
#pragma unroll
                for (int c = 0; c < 3; ++c) {
                    a0[j] = fmaf(v[r * 3 + c],       wc[r * 3 + c], a0[j]);
                    a1[j] = fmaf(v[(r + 2) * 3 + c], wc[r * 3 + c], a1[j]);
                }
            }
        }
    }
    const int p0 = y0 * WH + x;
#pragma unroll
    for (int j = 0; j < 8; ++j) {
        c2[(co0 + j) * NPH + p0]      = fmaxf(a0[j], 0.0f);
        c2[(co0 + j) * NPH + p0 + WH] = fmaxf(a1[j], 0.0f);
    }
}

// ---- up1 role: ConvTranspose2d(16->8,k3,s2,p1,op1) + s1 skip + relu -------
__device__ __forceinline__ void up1_role(
    const float* __restrict__ s2, const float* __restrict__ w,
    const float* __restrict__ b, const float* __restrict__ s1,
    float* __restrict__ ubuf, int pb)
{
    const int q = pb * 256 + threadIdx.x;  // < NPH
    const int r = q / WH, c = q - r * WH;
    const int dc = (c + 1 < WH) ? 1 : 0;
    const int dr = (r + 1 < HH) ? WH : 0;
    const float mc = (c + 1 < WH) ? 1.0f : 0.0f;
    const float mr = (r + 1 < HH) ? 1.0f : 0.0f;
    const float mrc = mc * mr;
    float a00[8], a01[8], a10[8], a11[8];
#pragma unroll
    for (int j = 0; j < 8; ++j) { a00[j] = b[j]; a01[j] = b[j]; a10[j] = b[j]; a11[j] = b[j]; }
#pragma unroll 2
    for (int ci = 0; ci < 16; ++ci) {
        const float* p = s2 + ci * NPH + r * WH + c;
        float v00 = p[0];
        float v01 = p[dc] * mc;
        float v10 = p[dr] * mr;
        float v11 = p[dr + dc] * mrc;
        const float* wp = w + ci * 8 * 9;
#pragma unroll
        for (int j = 0; j < 8; ++j) {
            const float* wc = wp + j * 9;
            a00[j] = fmaf(v00, wc[4], a00[j]);
            a01[j] = fmaf(v01, wc[3], fmaf(v00, wc[5], a01[j]));
            a10[j] = fmaf(v10, wc[1], fmaf(v00, wc[7], a10[j]));
            a11[j] = fmaf(v11, wc[0], fmaf(v10, wc[2], fmaf(v01, wc[6], fmaf(v00, wc[8], a11[j]))));
        }
    }
    const int o0 = (2 * r) * WF + 2 * c;
#pragma unroll
    for (int j = 0; j < 8; ++j) {
        int o = j * NPF + o0;
        ubuf[o]          = fmaxf(a00[j] + s1[o], 0.0f);
        ubuf[o + 1]      = fmaxf(a01[j] + s1[o + 1], 0.0f);
        ubuf[o + WF]     = fmaxf(a10[j] + s1[o + WF], 0.0f);
        ubuf[o + WF + 1] = fmaxf(a11[j] + s1[o + WF + 1], 0.0f);
    }
}

// ---- up2 role: ConvTranspose2d(8->1,k3,s2,p1,op1) -> out slice (512,640) --
__device__ __forceinline__ void up2_role(
    const float* __restrict__ u, const float* __restrict__ w,
    const float* __restrict__ b, float* __restrict__ oslice, int pb)
{
    const int q = pb * 256 + threadIdx.x;  // < NPF
    const int r = q / WF, c = q - r * WF;
    const int dc = (c + 1 < WF) ? 1 : 0;
    const int dr = (r + 1 < HF) ? WF : 0;
    const float mc = (c + 1 < WF) ? 1.0f : 0.0f;
    const float mr = (r + 1 < HF) ? 1.0f : 0.0f;
    const float mrc = mc * mr;
    const float b0 = b[0];
    float a00 = b0, a01 = b0, a10 = b0, a11 = b0;
#pragma unroll 2
    for (int ci = 0; ci < 8; ++ci) {
        const float* p = u + ci * NPF + r * WF + c;
        float v00 = p[0];
        float v01 = p[dc] * mc;
        float v10 = p[dr] * mr;
        float v11 = p[dr + dc] * mrc;
        const float* wc = w + ci * 9;
        a00 = fmaf(v00, wc[4], a00);
        a01 = fmaf(v01, wc[3], fmaf(v00, wc[5], a01));
        a10 = fmaf(v10, wc[1], fmaf(v00, wc[7], a10));
        a11 = fmaf(v11, wc[0], fmaf(v10, wc[2], fmaf(v01, wc[6], fmaf(v00, wc[8], a11))));
    }
    float* o = oslice + (2 * r) * 640 + 2 * c;
    o[0] = a00; o[1] = a01; o[640] = a10; o[641] = a11;
}

// ---- fused skewed-chain steps ---------------------------------------------
// A(d): gates1(d) [0,320) | gates2(d-2) [320,640) | up1(d-3) [640,720)
__global__ __launch_bounds__(256) void k_stepA(
    const float* __restrict__ c1_all, const float* __restrict__ s1_all,
    const float* __restrict__ wg1, const float* __restrict__ bg1,
    float* __restrict__ rh1, float* __restrict__ ug1,
    const float* __restrict__ c2_all, const float* __restrict__ s2_all,
    const float* __restrict__ wg2, const float* __restrict__ bg2,
    float* __restrict__ rh2, float* __restrict__ ug2,
    const float* __restrict__ wu1, const float* __restrict__ bu1,
    float* __restrict__ ubuf,
    int d1, int d2, int du1)
{
    const int bid = blockIdx.x;
    if (bid < 320) {
        if (d1 < 0) return;
        gates1_role(c1_all + (long)d1 * S1SZ, s1_all + (long)d1 * S1SZ,
                    wg1, bg1, rh1, ug1, bid);
    } else if (bid < 640) {
        if (d2 < 0) return;
        const int bb = bid - 320;
        gates2_role(c2_all + (long)d2 * S2SZ, s2_all + (long)d2 * S2SZ,
                    wg2, bg2, rh2, ug2, bb % 80, bb / 80);
    } else {
        if (du1 < 0) return;
        up1_role(s2_all + (long)(du1 + 1) * S2SZ, wu1, bu1,
                 s1_all + (long)(du1 + 1) * S1SZ, ubuf, bid - 640);
    }
}

// B(d): cand1(d) [0,160) | conv2(d-1) [160,240) | cand2(d-2) [240,400) |
//       conv1(d+2) [400,720) | up2(d-3) [720,1040)
__global__ __launch_bounds__(256) void k_stepB(
    const float* __restrict__ x, const float* __restrict__ w1,
    const float* __restrict__ b1, float* __restrict__ c1_all,
    float* __restrict__ s1_all,
    const float* __restrict__ wc1, const float* __restrict__ bc1,
    const float* __restrict__ rh1, const float* __restrict__ ug1,
    const float* __restrict__ w2, const float* __restrict__ b2,
    float* __restrict__ c2_all, float* __restrict__ s2_all,
    const float* __restrict__ wc2, const float* __restrict__ bc2,
    const float* __restrict__ rh2, const float* __restrict__ ug2,
    const float* __restrict__ wu2, const float* __restrict__ bu2,
    const float* __restrict__ ubuf, float* __restrict__ out,
    int d1, int dc, int d2, int dcv1, int du2)
{
    const int bid = blockIdx.x;
    if (bid < 160) {
        if (d1 < 0) return;
        cand1_role(c1_all + (long)d1 * S1SZ, rh1, wc1, bc1, ug1,
                   s1_all + (long)d1 * S1SZ, s1_all + (long)(d1 + 1) * S1SZ, bid);
    } else if (bid < 240) {
        if (dc < 0) return;
        const int bb = bid - 160;
        conv2_role(s1_all + (long)(dc + 1) * S1SZ, w2, b2,
                   c2_all + (long)dc * S2SZ, bb % 40, bb / 40);
    } else if (bid < 400) {
        if (d2 < 0) return;
        const int bb = bid - 240;
        cand2_role(c2_all + (long)d2 * S2SZ, rh2, wc2, bc2, ug2,
                   s2_all + (long)d2 * S2SZ, s2_all + (long)(d2 + 1) * S2SZ,
                   bb % 80, bb / 80);
    } else if (bid < 720) {
        if (dcv1 < 0) return;
        conv1p_role(x, w1, b1, c1_all + (long)dcv1 * S1SZ, dcv1, bid - 400);
    } else {
        if (du2 < 0) return;
        up2_role(ubuf, wu2, bu2, out + (long)du2 * (512 * 640), bid - 720);
    }
}

// ---- standalone wrappers (fallback path) ----------------------------------
__global__ __launch_bounds__(256) void k_gates1(
    const float* __restrict__ c1, const float* __restrict__ s1,
    const float* __restrict__ w, const float* __restrict__ b,
    float* __restrict__ rh, float* __restrict__ u)
{ gates1_role(c1, s1, w, b, rh, u, blockIdx.x); }

__global__ __launch_bounds__(256) void k_cand1(
    const float* __restrict__ a, const float* __restrict__ rh,
    const float* __restrict__ w, const float* __restrict__ b,
    const float* __restrict__ u, const float* __restrict__ sprev,
    float* __restrict__ sout)
{ cand1_role(a, rh, w, b, u, sprev, sout, blockIdx.x); }

__global__ __launch_bounds__(256) void k_gates2(
    const float* __restrict__ c2, const float* __restrict__ s2,
    const float* __restrict__ w, const float* __restrict__ b,
    float* __restrict__ rh, float* __restrict__ u)
{ gates2_role(c2, s2, w, b, rh, u, blockIdx.x % 80, blockIdx.x / 80); }

__global__ __launch_bounds__(256) void k_cand2(
    const float* __restrict__ a, const float* __restrict__ rh,
    const float* __restrict__ w, const float* __restrict__ b,
    const float* __restrict__ u, const float* __restrict__ sprev,
    float* __restrict__ sout)
{ cand2_role(a, rh, w, b, u, sprev, sout, blockIdx.x % 80, blockIdx.x / 80); }

__global__ __launch_bounds__(256) void k_conv2w(
    const float* __restrict__ s1, const float* __restrict__ w,
    const float* __restrict__ b, float* __restrict__ c2)
{ conv2_role(s1, w, b, c2, blockIdx.x, blockIdx.y); }

__global__ __launch_bounds__(256) void k_up1(
    const float* __restrict__ s2b, int zs2,
    const float* __restrict__ w, const float* __restrict__ b,
    const float* __restrict__ s1b, int zs1,
    float* __restrict__ ub, int zu)
{
    up1_role(s2b + (long)blockIdx.z * zs2, w, b,
             s1b + (long)blockIdx.z * zs1, ub + (long)blockIdx.z * zu, blockIdx.x);
}

__global__ __launch_bounds__(256) void k_up2(
    const float* __restrict__ ub, int zu,
    const float* __restrict__ w, const float* __restrict__ b,
    float* __restrict__ out, int d0)
{
    up2_role(ub + (long)blockIdx.z * zu, w, b,
             out + (long)(d0 + blockIdx.z) * (512 * 640), blockIdx.x);
}

extern "C" void kernel_launch(void* const* d_in, const int* in_sizes, int n_in,
                              void* d_out, int out_size, void* d_ws, size_t ws_size,
                              hipStream_t stream)
{
    const float* x   = (const float*)d_in[0];
    const float* w1  = (const float*)d_in[1];
    const float* b1  = (const float*)d_in[2];
    const float* wg1 = (const float*)d_in[3];
    const float* bg1 = (const float*)d_in[4];
    const float* wc1 = (const float*)d_in[5];
    const float* bc1 = (const float*)d_in[6];
    const float* w2  = (const float*)d_in[7];
    const float* b2  = (const float*)d_in[8];
    const float* wg2 = (const float*)d_in[9];
    const float* bg2 = (const float*)d_in[10];
    const float* wc2 = (const float*)d_in[11];
    const float* bc2 = (const float*)d_in[12];
    const float* wu1 = (const float*)d_in[13];
    const float* bu1 = (const float*)d_in[14];
    const float* wu2 = (const float*)d_in[15];
    const float* bu2 = (const float*)d_in[16];
    float* out = (float*)d_out;
    float* ws = (float*)d_ws;

    // ---- full-history schedule: skewed fused chains, balanced A/B ----
    {
        float* p = ws;
        float* s1_all = p; p += 49L * S1SZ;   // slice 0 = zeros
        float* s2_all = p; p += 49L * S2SZ;
        float* c2_all = p; p += 48L * S2SZ;
        float* rh1 = p; p += S1SZ;
        float* ug1 = p; p += S1SZ;
        float* rh2 = p; p += S2SZ;
        float* ug2 = p; p += S2SZ;
        float* ubuf = p; p += S1SZ;           // single up1->up2 slice (A(d)->B(d))
        float* c1_all = p; p += 48L * S1SZ;
        const size_t need = (size_t)(p - ws) * sizeof(float);
        if (ws_size >= need) {
            hipMemsetAsync(s1_all, 0, (size_t)S1SZ * sizeof(float), stream);
            hipMemsetAsync(s2_all, 0, (size_t)S2SZ * sizeof(float), stream);

            // Prologue: conv1 for slices 0,1 (chain folds in slice d+2).
            k_conv1<<<dim3(80, 1, 2), 256, 0, stream>>>(x, w1, b1, c1_all, 0, S1SZ);
            // Skew (all producers >= 1 dispatch ahead of consumers):
            //   A(d): gates1(d) | gates2(d-2) | up1(d-3)
            //   B(d): cand1(d) | conv2(d-1) | cand2(d-2) | conv1(d+2) | up2(d-3)
            // conv1(d+2) in B(d) precedes gates1(d+2) in A(d+2) and
            // cand1(d+2) in B(d+2) by >=2 dispatches.
            for (int d = 0; d <= 50; ++d) {
                const int g1  = (d <= 47) ? d : -1;
                const int g2  = (d >= 2 && d <= 49) ? d - 2 : -1;
                const int cv  = (d >= 1 && d <= 48) ? d - 1 : -1;
                const int cv1 = (d <= 45) ? d + 2 : -1;
                const int u1  = (d >= 3) ? d - 3 : -1;   // <= 47 since d <= 50
                k_stepA<<<dim3(720), 256, 0, stream>>>(
                    c1_all, s1_all, wg1, bg1, rh1, ug1,
                    c2_all, s2_all, wg2, bg2, rh2, ug2,
                    wu1, bu1, ubuf, g1, g2, u1);
                k_stepB<<<dim3(1040), 256, 0, stream>>>(
                    x, w1, b1, c1_all, s1_all, wc1, bc1, rh1, ug1,
                    w2, b2, c2_all, s2_all, wc2, bc2, rh2, ug2,
                    wu2, bu2, ubuf, out, g1, cv, g2, cv1, u1);
            }
            return;
        }
    }

    // ---- fallback: small-workspace interleaved schedule ----
    {
        float* p = ws;
        float* s1 = p; p += S1SZ;
        float* s2 = p; p += S2SZ;
        float* rh1 = p; p += S1SZ;
        float* ug1 = p; p += S1SZ;
        float* c2 = p; p += S2SZ;
        float* rh2 = p; p += S2SZ;
        float* ug2 = p; p += S2SZ;
        float* c1 = p; p += S1SZ;
        float* u = p; p += S1SZ;
        hipMemsetAsync(s1, 0, (size_t)S1SZ * sizeof(float), stream);
        hipMemsetAsync(s2, 0, (size_t)S2SZ * sizeof(float), stream);
        for (int d = 0; d < 48; ++d) {
            k_conv1<<<dim3(80, 1, 1), 256, 0, stream>>>(x, w1, b1, c1, d, 0);
            k_gates1<<<dim3(320), 256, 0, stream>>>(c1, s1, wg1, bg1, rh1, ug1);
            k_cand1<<<dim3(160), 256, 0, stream>>>(c1, rh1, wc1, bc1, ug1, s1, s1);
            k_conv2w<<<dim3(40, 2), 256, 0, stream>>>(s1, w2, b2, c2);
            k_gates2<<<dim3(320), 256, 0, stream>>>(c2, s2, wg2, bg2, rh2, ug2);
            k_cand2<<<dim3(160), 256, 0, stream>>>(c2, rh2, wc2, bc2, ug2, s2, s2);
            k_up1<<<dim3(80, 1, 1), 256, 0, stream>>>(s2, 0, wu1, bu1, s1, 0, u, 0);
            k_up2<<<dim3(320, 1, 1), 256, 0, stream>>>(u, 0, wu2, bu2, out, d);
        }
    }
}